// Round 2
// baseline (928.269 us; speedup 1.0000x reference)
//
#include <hip/hip_runtime.h>
#include <hip/hip_bf16.h>
#include <hip/hip_fp16.h>
#include <stdint.h>

#define N_NODES 100000
#define N_EDGES 1600000
#define IN_DIM 256
#define HID 128
#define N_LAYERS 4
#define OUT_DIM 7
#define LN_EPS 1e-5f

#define SCAN_B 1024
#define SCAN_NB ((N_NODES + SCAN_B - 1) / SCAN_B)   // 98

// edge bucketing: 64 rows per bucket
#define BSHIFT 6
#define BROWS 64
#define NBK 1563          // ceil(100000/64)
#define BCAP 1408         // mean 1024 + 12 sigma (binomial), overflow ~impossible

typedef __attribute__((ext_vector_type(8))) short bf16x8;
typedef __attribute__((ext_vector_type(4))) float f32x4;

__device__ inline float bf2f1(uint16_t u) {
    union { uint32_t i; float f; } a; a.i = ((uint32_t)u) << 16; return a.f;
}
__device__ inline uint16_t f2bf(float f) {
    union { float f; uint32_t i; } a; a.f = f;
    uint32_t lsb = (a.i >> 16) & 1u;
    a.i += 0x7fffu + lsb;          // round-to-nearest-even
    return (uint16_t)(a.i >> 16);
}
__device__ inline uint32_t packq(float a, float b, float qinv) {
    int qa = __float2int_rn(a * qinv);
    int qb = __float2int_rn(b * qinv);
    return ((uint32_t)(uint16_t)(short)qa) | (((uint32_t)(uint16_t)(short)qb) << 16);
}

// ---------------- dtype detection ----------------
__global__ void k_detect(const uint32_t* __restrict__ W, int* __restrict__ flag) {
    if (threadIdx.x == 0 && blockIdx.x == 0) {
        int cnt = 0;
        for (int i = 0; i < 64; i++) {
            uint32_t lo = W[i] & 0xffffu;
            uint32_t ex = (lo >> 7) & 0xff;
            if (ex >= 0x60 && ex < 0x7c) cnt++;
        }
        *flag = (cnt < 32) ? 1 : 0;   // 1 = fp32 inputs, 0 = bf16 inputs
    }
}

// ---------------- weight canonicalization (all weights -> fp32 staged) ----------------
__global__ __launch_bounds__(256) void k_cvt(const void* a0, const void* a1, const void* a2,
                                             const void* a3, const void* a4, const void* a5,
                                             const void* a6, const void* a7, const void* a8,
                                             float* __restrict__ dst, const int* __restrict__ flag) {
    int t = blockIdx.x * 256 + threadIdx.x;
    if (t >= 99720) return;
    const void* src; int i; int off;
    if      (t < 32768) { src = a0; i = t;         off = 0;     }   // W_proj 256x128
    else if (t < 32896) { src = a1; i = t - 32768; off = 32768; }   // b_proj 128
    else if (t < 33024) { src = a2; i = t - 32896; off = 32896; }   // gamma 128
    else if (t < 33152) { src = a3; i = t - 33024; off = 33024; }   // beta 128
    else if (t < 33280) { src = a4; i = t - 33152; off = 33152; }   // q_w 128
    else if (t < 33281) { src = a5; i = t - 33280; off = 33280; }   // q_b 1
    else if (t < 98817) { src = a6; i = t - 33281; off = 33296; }   // conv_w 4x128x128
    else if (t < 99713) { src = a7; i = t - 98817; off = 98832; }   // cls_w 128x7
    else                { src = a8; i = t - 99713; off = 99728; }   // cls_b 7
    float v;
    if (*flag) v = ((const float*)src)[i];
    else       v = bf2f1(((const uint16_t*)src)[i]);
    dst[off + i] = v;
}

// ---------------- split-bf16 transposed weight prep ----------------
__global__ __launch_bounds__(256) void k_wsplit(const float* __restrict__ stg,
                                                uint16_t* __restrict__ wpThi, uint16_t* __restrict__ wpTlo,
                                                uint16_t* __restrict__ cwThi, uint16_t* __restrict__ cwTlo) {
    int t = blockIdx.x * 256 + threadIdx.x;
    if (t >= 32768 + 65536) return;
    float v; size_t dst; uint16_t *ha, *la;
    if (t < 32768) {
        int k = t >> 7, c = t & 127;
        v = stg[t];
        dst = (size_t)c * 256 + k; ha = wpThi; la = wpTlo;
    } else {
        int u = t - 32768;
        int L = u >> 14, rem = u & 16383;
        int k = rem >> 7, c = rem & 127;
        v = stg[33296 + u];
        dst = (size_t)L * 16384 + (size_t)c * 128 + k; ha = cwThi; la = cwTlo;
    }
    uint16_t hb = f2bf(v);
    uint16_t lb = f2bf(v - bf2f1(hb));
    ha[dst] = hb; la[dst] = lb;
}

// ---------------- graph prep: bucketed CSR build ----------------

// pass P: partition edges into row-buckets (cursor-sequential writes, hot counters)
__global__ __launch_bounds__(256) void k_part(const int* __restrict__ row, const int* __restrict__ col,
                                              int* __restrict__ bcnt, int2* __restrict__ eb) {
    int e = blockIdx.x * 256 + threadIdx.x;
    if (e >= N_EDGES) return;
    int r = row[e], c = col[e];
    int b = r >> BSHIFT;
    int pos = atomicAdd(&bcnt[b], 1);
    if (pos < BCAP) eb[(size_t)b * BCAP + pos] = make_int2(r, c);
}

// pass D: per-bucket degree via LDS atomics (replaces global-atomic k_deg)
__global__ __launch_bounds__(256) void k_bdeg(const int2* __restrict__ eb, const int* __restrict__ bcnt,
                                              int* __restrict__ deg) {
    __shared__ int ld[BROWS];
    int b = blockIdx.x, tid = threadIdx.x;
    if (tid < BROWS) ld[tid] = 0;
    __syncthreads();
    int n = bcnt[b]; if (n > BCAP) n = BCAP;
    const int2* base = eb + (size_t)b * BCAP;
    for (int i = tid; i < n; i += 256) atomicAdd(&ld[base[i].x & (BROWS - 1)], 1);
    __syncthreads();
    int r = (b << BSHIFT) + tid;
    if (tid < BROWS && r < N_NODES) deg[r] = ld[tid];
}

__global__ __launch_bounds__(SCAN_B) void k_scan1(const int* __restrict__ deg,
                                                  int* __restrict__ incl, int* __restrict__ bsum) {
    __shared__ int sm[SCAN_B];
    int t = threadIdx.x;
    int i = blockIdx.x * SCAN_B + t;
    int v = (i < N_NODES) ? deg[i] : 0;
    sm[t] = v;
    __syncthreads();
    for (int off = 1; off < SCAN_B; off <<= 1) {
        int add = (t >= off) ? sm[t - off] : 0;
        __syncthreads();
        sm[t] += add;
        __syncthreads();
    }
    if (i < N_NODES) incl[i] = sm[t];
    if (t == SCAN_B - 1) bsum[blockIdx.x] = sm[t];
}

__global__ __launch_bounds__(128) void k_scan2(const int* __restrict__ bsum, int* __restrict__ boff) {
    __shared__ int s[SCAN_NB];
    int t = threadIdx.x;
    if (t < SCAN_NB) s[t] = bsum[t];
    __syncthreads();
    if (t == 0) {
        int run = 0;
        for (int b = 0; b < SCAN_NB; b++) { int v = s[b]; s[b] = run; run += v; }
    }
    __syncthreads();
    if (t < SCAN_NB) boff[t] = s[t];
}

__global__ __launch_bounds__(256) void k_scan3(const int* __restrict__ deg, const int* __restrict__ incl,
                                               const int* __restrict__ boff,
                                               int* __restrict__ rp, float* __restrict__ dis) {
    int i = blockIdx.x * 256 + threadIdx.x;
    if (i >= N_NODES) return;
    int d = deg[i];
    int excl = boff[i / SCAN_B] + incl[i] - d;
    rp[i] = excl;
    if (i == N_NODES - 1) rp[N_NODES] = excl + d;
    dis[i] = rsqrtf((float)(d > 0 ? d : 1));
}

// pass Q: per-bucket final scatter with LDS cursors (no global atomics, 4KB write window)
__global__ __launch_bounds__(256) void k_bscat(const int2* __restrict__ eb, const int* __restrict__ bcnt,
                                               const int* __restrict__ rp, int* __restrict__ edc) {
    __shared__ int lcur[BROWS];
    int b = blockIdx.x, tid = threadIdx.x;
    int row0 = b << BSHIFT;
    if (tid < BROWS) lcur[tid] = (row0 + tid < N_NODES) ? rp[row0 + tid] : 0;
    __syncthreads();
    int n = bcnt[b]; if (n > BCAP) n = BCAP;
    const int2* base = eb + (size_t)b * BCAP;
    for (int i = tid; i < n; i += 256) {
        int2 rc = base[i];
        int pos = atomicAdd(&lcur[rc.x & (BROWS - 1)], 1);
        edc[pos] = rc.y;
    }
}

// ---------------- fused SpMM + blend ----------------
// one wave per node; lane holds cols {lane, lane+64}.
// edge = col only; weight = ScD[c] (= quantScale*dis folded), row factor dis[r] applied once.

__global__ __launch_bounds__(256) void k_spmm(const uint32_t* __restrict__ Hq,
                                              const float* __restrict__ ScD,
                                              const float* __restrict__ H0,
                                              const int* __restrict__ rp,
                                              const int* __restrict__ edc,
                                              const float* __restrict__ S,
                                              const float* __restrict__ dis,
                                              float* __restrict__ Sup) {
    int wid  = (blockIdx.x * 256 + threadIdx.x) >> 6;
    int lane = threadIdx.x & 63;
    if (wid >= N_NODES) return;

    float s  = S[wid];
    float dr = dis[wid];

    int p0 = rp[wid], p1 = rp[wid + 1];
    float ax = 0.f, ay = 0.f;
    int p = p0;
    for (; p + 4 <= p1; p += 4) {
        int c0 = edc[p], c1 = edc[p + 1], c2 = edc[p + 2], c3 = edc[p + 3];
        uint32_t u0 = Hq[(size_t)c0 * 64 + lane];
        uint32_t u1 = Hq[(size_t)c1 * 64 + lane];
        uint32_t u2 = Hq[(size_t)c2 * 64 + lane];
        uint32_t u3 = Hq[(size_t)c3 * 64 + lane];
        float w0 = ScD[c0], w1 = ScD[c1], w2 = ScD[c2], w3 = ScD[c3];
        ax += w0 * (float)((int)(u0 << 16) >> 16) + w1 * (float)((int)(u1 << 16) >> 16)
            + w2 * (float)((int)(u2 << 16) >> 16) + w3 * (float)((int)(u3 << 16) >> 16);
        ay += w0 * (float)((int)u0 >> 16) + w1 * (float)((int)u1 >> 16)
            + w2 * (float)((int)u2 >> 16) + w3 * (float)((int)u3 >> 16);
    }
    for (; p < p1; p++) {
        int c = edc[p];
        uint32_t u = Hq[(size_t)c * 64 + lane];
        float w = ScD[c];
        ax += w * (float)((int)(u << 16) >> 16);
        ay += w * (float)((int)u >> 16);
    }
    float h0x = H0[(size_t)wid * 128 + lane];
    float h0y = H0[(size_t)wid * 128 + 64 + lane];
    float f = (1.f - s) * dr;
    Sup[(size_t)wid * 128 + lane]      = f * ax + s * h0x;
    Sup[(size_t)wid * 128 + 64 + lane] = f * ay + s * h0y;
}

// ---------------- split-bf16 MFMA GEMM + fused LN + gate + quant ----------------
// Block = 64 rows x 128 cols, 256 threads = 4 waves; wave w owns rows [w*16, w*16+16).
// C layout: col = lane&15, row = (lane>>4)*4 + reg.  Split: C = Ah*Wh + Ah*Wl + Al*Wh.
// LDS tiles XOR-swizzled (byte ^= (row&7)<<4), applied identically on write and read.
// NOTE: Hout may alias Araw for MODE 1 (each block only touches its own 64 rows).

template <int KD, int MODE, int WH, int WQ>
__global__ __launch_bounds__(256) void k_gemm_mfma(
    const void* __restrict__ Araw,       // [N][KD] fp32 (or bf16 if MODE0 && !flag)
    const uint16_t* __restrict__ WThi,   // [128][KD] bf16 hi (transposed)
    const uint16_t* __restrict__ WTlo,   // [128][KD] bf16 lo
    const float* __restrict__ bias, const float* __restrict__ gamma,
    const float* __restrict__ beta, const float* __restrict__ qw,
    const float* __restrict__ qb, float theta, const int* __restrict__ flag,
    const float* __restrict__ dis,
    float* __restrict__ Hout, uint32_t* __restrict__ Hq,
    float* __restrict__ Sc, float* __restrict__ S)
{
    __shared__ __align__(16) uint16_t sAhi[64 * 64];    // 8 KiB
    __shared__ __align__(16) uint16_t sAlo[64 * 64];    // 8 KiB
    __shared__ __align__(16) uint16_t sBhi[128 * 64];   // 16 KiB
    __shared__ __align__(16) uint16_t sBlo[128 * 64];   // 16 KiB  -> 48 KiB total

    const int tid  = threadIdx.x;
    const int lane = tid & 63;
    const int wv   = tid >> 6;
    const int li   = lane & 15;
    const int lg   = lane >> 4;
    const size_t row0 = (size_t)blockIdx.x * 64;
    const int f32in = (MODE == 0) ? *flag : 1;

    f32x4 acc[8];
#pragma unroll
    for (int ct = 0; ct < 8; ct++) acc[ct] = (f32x4){0.f, 0.f, 0.f, 0.f};

    for (int kc = 0; kc < KD / 64; kc++) {
        __syncthreads();
        // ---- stage A (64 rows x 64 k) as hi/lo bf16, swizzled ----
#pragma unroll
        for (int it = 0; it < 2; it++) {
            int s  = tid + it * 256;
            int r  = s >> 3, sl = s & 7;
            size_t rg = row0 + r; if (rg >= N_NODES) rg = N_NODES - 1;
            uint4 vh, vl;
            if (f32in) {
                const float* p = (const float*)Araw + rg * KD + kc * 64 + sl * 8;
                float4 u0 = *(const float4*)p;
                float4 u1 = *(const float4*)(p + 4);
                float f[8] = {u0.x, u0.y, u0.z, u0.w, u1.x, u1.y, u1.z, u1.w};
                uint32_t hw[8], lw[8];
#pragma unroll
                for (int j = 0; j < 8; j++) {
                    uint16_t hb = f2bf(f[j]);
                    uint16_t lb = f2bf(f[j] - bf2f1(hb));
                    hw[j] = hb; lw[j] = lb;
                }
                vh.x = hw[0] | (hw[1] << 16); vh.y = hw[2] | (hw[3] << 16);
                vh.z = hw[4] | (hw[5] << 16); vh.w = hw[6] | (hw[7] << 16);
                vl.x = lw[0] | (lw[1] << 16); vl.y = lw[2] | (lw[3] << 16);
                vl.z = lw[4] | (lw[5] << 16); vl.w = lw[6] | (lw[7] << 16);
            } else {
                vh = *(const uint4*)((const uint16_t*)Araw + rg * KD + kc * 64 + sl * 8);
                vl.x = 0u; vl.y = 0u; vl.z = 0u; vl.w = 0u;
            }
            uint32_t byte = (uint32_t)(r * 128 + sl * 16) ^ (uint32_t)((r & 7) << 4);
            *(uint4*)((char*)sAhi + byte) = vh;
            *(uint4*)((char*)sAlo + byte) = vl;
        }
        // ---- stage W^T (128 cols x 64 k), swizzled ----
#pragma unroll
        for (int it = 0; it < 4; it++) {
            int s = tid + it * 256;
            int r = s >> 3, sl = s & 7;
            size_t gsrc = (size_t)r * KD + kc * 64 + sl * 8;
            uint4 vh = *(const uint4*)(WThi + gsrc);
            uint4 vl = *(const uint4*)(WTlo + gsrc);
            uint32_t byte = (uint32_t)(r * 128 + sl * 16) ^ (uint32_t)((r & 7) << 4);
            *(uint4*)((char*)sBhi + byte) = vh;
            *(uint4*)((char*)sBlo + byte) = vl;
        }
        __syncthreads();
        // ---- MFMA: 2 K-steps of 32 per chunk ----
#pragma unroll
        for (int ks = 0; ks < 2; ks++) {
            int arow = wv * 16 + li;
            uint32_t ab = (uint32_t)(arow * 128 + ks * 64 + lg * 16) ^ (uint32_t)((arow & 7) << 4);
            bf16x8 ah = *(const bf16x8*)((const char*)sAhi + ab);
            bf16x8 al = *(const bf16x8*)((const char*)sAlo + ab);
#pragma unroll
            for (int ct = 0; ct < 8; ct++) {
                int brow = ct * 16 + li;
                uint32_t bb = (uint32_t)(brow * 128 + ks * 64 + lg * 16) ^ (uint32_t)((brow & 7) << 4);
                bf16x8 bh = *(const bf16x8*)((const char*)sBhi + bb);
                bf16x8 bl = *(const bf16x8*)((const char*)sBlo + bb);
                acc[ct] = __builtin_amdgcn_mfma_f32_16x16x32_bf16(ah, bh, acc[ct], 0, 0, 0);
                acc[ct] = __builtin_amdgcn_mfma_f32_16x16x32_bf16(ah, bl, acc[ct], 0, 0, 0);
                acc[ct] = __builtin_amdgcn_mfma_f32_16x16x32_bf16(al, bh, acc[ct], 0, 0, 0);
            }
        }
    }

    // ---- epilogue ----
    float gm[8], bt[8], qv[8], bi[8];
#pragma unroll
    for (int ct = 0; ct < 8; ct++) {
        int c = ct * 16 + li;
        gm[ct] = gamma[c]; bt[ct] = beta[c]; qv[ct] = qw[c];
        bi[ct] = (MODE == 0) ? bias[c] : 0.f;
    }
    const float qbv = qb[0];
    const float om  = 1.f - theta;
    const float* Af = (const float*)Araw;

#pragma unroll
    for (int r = 0; r < 4; r++) {
        int rowl  = wv * 16 + lg * 4 + r;
        size_t rg = row0 + rowl;
        size_t rc = (rg < N_NODES) ? rg : (N_NODES - 1);
        float v[8];
        if (MODE == 0) {
#pragma unroll
            for (int ct = 0; ct < 8; ct++) v[ct] = acc[ct][r] + bi[ct];
        } else {
#pragma unroll
            for (int ct = 0; ct < 8; ct++) {
                float sv = Af[rc * KD + ct * 16 + li];   // support re-read (L1/L2-hot)
                float o  = theta * acc[ct][r] + om * sv;
                v[ct] = o > 0.f ? o : 0.f;
            }
        }
        float sum = 0.f, sq = 0.f;
#pragma unroll
        for (int ct = 0; ct < 8; ct++) { sum += v[ct]; sq += v[ct] * v[ct]; }
        sum += __shfl_xor(sum, 1); sum += __shfl_xor(sum, 2);
        sum += __shfl_xor(sum, 4); sum += __shfl_xor(sum, 8);
        sq  += __shfl_xor(sq, 1);  sq  += __shfl_xor(sq, 2);
        sq  += __shfl_xor(sq, 4);  sq  += __shfl_xor(sq, 8);
        float mu  = sum * (1.f / 128.f);
        float var = fmaxf(sq * (1.f / 128.f) - mu * mu, 0.f);
        float rs  = rsqrtf(var + LN_EPS);
        float y[8];
#pragma unroll
        for (int ct = 0; ct < 8; ct++) y[ct] = gm[ct] * (v[ct] - mu) * rs + bt[ct];

        if (WQ) {
            float zd = 0.f, am = 0.f;
#pragma unroll
            for (int ct = 0; ct < 8; ct++) { zd += y[ct] * qv[ct]; am = fmaxf(am, fabsf(y[ct])); }
            zd += __shfl_xor(zd, 1); zd += __shfl_xor(zd, 2);
            zd += __shfl_xor(zd, 4); zd += __shfl_xor(zd, 8);
            am = fmaxf(am, __shfl_xor(am, 1)); am = fmaxf(am, __shfl_xor(am, 2));
            am = fmaxf(am, __shfl_xor(am, 4)); am = fmaxf(am, __shfl_xor(am, 8));
            float amc  = fmaxf(am, 1e-20f);
            float qinv = 32767.f / amc;
            if (rg < N_NODES) {
                uint32_t* mq = Hq + rg * 64;
#pragma unroll
                for (int ct = 0; ct < 4; ct++)
                    mq[ct * 16 + li] = packq(y[ct], y[ct + 4], qinv);  // pair (c, c+64)
                if (li == 0) {
                    Sc[rg] = amc * (1.f / 32767.f) * dis[rg];   // fold dis[col] into scale
                    S[rg]  = 1.f / (1.f + __expf(-(zd + qbv - 1.f)));
                }
            }
        }
        if (WH && rg < N_NODES) {
            float* dst = Hout + rg * 128;
#pragma unroll
            for (int ct = 0; ct < 8; ct++) dst[ct * 16 + li] = y[ct];
        }
    }
}

// ---------------- classifier (fp32 in, dtype-flag out) ----------------

__global__ __launch_bounds__(256) void k_cls(const float* __restrict__ H,
                                             const float* __restrict__ Wc,
                                             const float* __restrict__ bc,
                                             const int* __restrict__ flag,
                                             void* __restrict__ out) {
    __shared__ float wS[128][8];
    int tid = threadIdx.x;
    for (int idx = tid; idx < 128 * 7; idx += 256) wS[idx / 7][idx % 7] = Wc[idx];
    __syncthreads();
    int isf32 = *flag;
    int gid = blockIdx.x * 256 + tid;
    int n = gid >> 3, j = gid & 7;
    if (n >= N_NODES || j >= OUT_DIM) return;
    const float4* hr = (const float4*)(H + (size_t)n * 128);
    float acc = bc[j];
#pragma unroll
    for (int k4 = 0; k4 < 32; k4++) {
        float4 h4 = hr[k4];
        acc += h4.x * wS[4 * k4][j]     + h4.y * wS[4 * k4 + 1][j]
             + h4.z * wS[4 * k4 + 2][j] + h4.w * wS[4 * k4 + 3][j];
    }
    size_t oi = (size_t)n * OUT_DIM + j;
    if (isf32) ((float*)out)[oi] = acc;
    else       ((uint16_t*)out)[oi] = f2bf(acc);
}

// ---------------- launch ----------------

extern "C" void kernel_launch(void* const* d_in, const int* in_sizes, int n_in,
                              void* d_out, int out_size, void* d_ws, size_t ws_size,
                              hipStream_t stream) {
    const void* x_raw = d_in[0];
    const int*  ei    = (const int*)d_in[1];
    const int* row = ei;
    const int* col = ei + N_EDGES;

    char* ws = (char*)d_ws;
    size_t off = 0;
    auto alloc = [&](size_t b) { void* p = ws + off; off = (off + b + 255) & ~(size_t)255; return p; };
    int*      flag = (int*)alloc(4);
    float*    stgf = (float*)alloc((size_t)99744 * 4);
    int*      deg  = (int*)alloc((size_t)N_NODES * 4);
    int*      rp   = (int*)alloc(((size_t)N_NODES + 1) * 4);
    float*    dis  = (float*)alloc((size_t)N_NODES * 4);
    int*      incl = (int*)alloc((size_t)N_NODES * 4);
    int*      bsum = (int*)alloc((size_t)SCAN_NB * 4);
    int*      boff = (int*)alloc((size_t)SCAN_NB * 4);
    int*      bcnt = (int*)alloc((size_t)NBK * 4);
    int*      edc  = (int*)alloc((size_t)N_EDGES * 4);            // CSR cols (4B)
    float*    h0   = (float*)alloc((size_t)N_NODES * HID * 4);
    float*    sup  = (float*)alloc((size_t)N_NODES * HID * 4);    // also final h (in-place)
    uint32_t* hq   = (uint32_t*)alloc((size_t)N_NODES * 64 * 4);  // int16 mirror
    float*    Scq  = (float*)alloc((size_t)N_NODES * 4);          // quant scale * dis
    float*    Sg   = (float*)alloc((size_t)N_NODES * 4);          // gate sigmoid
    uint16_t* wpThi = (uint16_t*)alloc((size_t)32768 * 2);
    uint16_t* wpTlo = (uint16_t*)alloc((size_t)32768 * 2);
    uint16_t* cwThi = (uint16_t*)alloc((size_t)65536 * 2);
    uint16_t* cwTlo = (uint16_t*)alloc((size_t)65536 * 2);
    int2*     eb   = (int2*)h0;   // bucket staging (17.6MB) aliases h0 (written after prep)

    const float* bp  = stgf + 32768;
    const float* gm  = stgf + 32896;
    const float* bt  = stgf + 33024;
    const float* qw  = stgf + 33152;
    const float* qb  = stgf + 33280;
    const float* clw = stgf + 98832;
    const float* clb = stgf + 99728;

    k_detect<<<1, 64, 0, stream>>>((const uint32_t*)d_in[2], flag);
    k_cvt<<<(99720 + 255) / 256, 256, 0, stream>>>(d_in[2], d_in[3], d_in[4], d_in[5], d_in[6],
                                                   d_in[7], d_in[8], d_in[9], d_in[10], stgf, flag);
    k_wsplit<<<(98304 + 255) / 256, 256, 0, stream>>>(stgf, wpThi, wpTlo, cwThi, cwTlo);

    hipMemsetAsync(bcnt, 0, (size_t)NBK * 4, stream);
    k_part<<<(N_EDGES + 255) / 256, 256, 0, stream>>>(row, col, bcnt, eb);
    k_bdeg<<<NBK, 256, 0, stream>>>(eb, bcnt, deg);
    k_scan1<<<SCAN_NB, SCAN_B, 0, stream>>>(deg, incl, bsum);
    k_scan2<<<1, 128, 0, stream>>>(bsum, boff);
    k_scan3<<<(N_NODES + 255) / 256, 256, 0, stream>>>(deg, incl, boff, rp, dis);
    k_bscat<<<NBK, 256, 0, stream>>>(eb, bcnt, rp, edc);

    const int gemm_grid = (N_NODES + 63) / 64;   // 1563
    k_gemm_mfma<IN_DIM, 0, 1, 1><<<gemm_grid, 256, 0, stream>>>(
        x_raw, wpThi, wpTlo, bp, gm, bt, qw, qb, 0.f, flag, dis, h0, hq, Scq, Sg);

    for (int i = 0; i < N_LAYERS; i++) {
        k_spmm<<<(N_NODES + 3) / 4, 256, 0, stream>>>(hq, Scq, h0, rp, edc, Sg, dis, sup);
        float theta = 0.5f / (float)(i + 1);
        const uint16_t* whi = cwThi + (size_t)i * 16384;
        const uint16_t* wlo = cwTlo + (size_t)i * 16384;
        if (i < N_LAYERS - 1) {
            k_gemm_mfma<HID, 1, 0, 1><<<gemm_grid, 256, 0, stream>>>(
                sup, whi, wlo, nullptr, gm, bt, qw, qb, theta, flag, dis, sup, hq, Scq, Sg);
        } else {
            k_gemm_mfma<HID, 1, 1, 0><<<gemm_grid, 256, 0, stream>>>(
                sup, whi, wlo, nullptr, gm, bt, qw, qb, theta, flag, dis, sup, hq, Scq, Sg);
        }
    }
    k_cls<<<((size_t)N_NODES * 8 + 255) / 256, 256, 0, stream>>>(sup, clw, clb, flag, d_out);
}

// Round 3
// 755.015 us; speedup vs baseline: 1.2295x; 1.2295x over previous
//
#include <hip/hip_runtime.h>
#include <hip/hip_bf16.h>
#include <hip/hip_fp16.h>
#include <stdint.h>

#define N_NODES 100000
#define N_EDGES 1600000
#define IN_DIM 256
#define HID 128
#define N_LAYERS 4
#define OUT_DIM 7
#define LN_EPS 1e-5f

// counting-sort CSR build
#define BSHIFT 6
#define BROWS 64
#define NBK 1563                  // ceil(100000/64) buckets of 64 rows
#define CHUNK 16384               // edges per sort block
#define NCH ((N_EDGES + CHUNK - 1) / CHUNK)   // 98 (must be <= 128 for k_hscan)

typedef __attribute__((ext_vector_type(8))) short bf16x8;
typedef __attribute__((ext_vector_type(4))) float f32x4;

__device__ inline float bf2f1(uint16_t u) {
    union { uint32_t i; float f; } a; a.i = ((uint32_t)u) << 16; return a.f;
}
__device__ inline uint16_t f2bf(float f) {
    union { float f; uint32_t i; } a; a.f = f;
    uint32_t lsb = (a.i >> 16) & 1u;
    a.i += 0x7fffu + lsb;          // round-to-nearest-even
    return (uint16_t)(a.i >> 16);
}
__device__ inline uint32_t packq(float a, float b, float qinv) {
    int qa = __float2int_rn(a * qinv);
    int qb = __float2int_rn(b * qinv);
    return ((uint32_t)(uint16_t)(short)qa) | (((uint32_t)(uint16_t)(short)qb) << 16);
}

// ---------------- dtype detection ----------------
__global__ void k_detect(const uint32_t* __restrict__ W, int* __restrict__ flag) {
    if (threadIdx.x == 0 && blockIdx.x == 0) {
        int cnt = 0;
        for (int i = 0; i < 64; i++) {
            uint32_t lo = W[i] & 0xffffu;
            uint32_t ex = (lo >> 7) & 0xff;
            if (ex >= 0x60 && ex < 0x7c) cnt++;
        }
        *flag = (cnt < 32) ? 1 : 0;   // 1 = fp32 inputs, 0 = bf16 inputs
    }
}

// ---------------- weight canonicalization (all weights -> fp32 staged) ----------------
__global__ __launch_bounds__(256) void k_cvt(const void* a0, const void* a1, const void* a2,
                                             const void* a3, const void* a4, const void* a5,
                                             const void* a6, const void* a7, const void* a8,
                                             float* __restrict__ dst, const int* __restrict__ flag) {
    int t = blockIdx.x * 256 + threadIdx.x;
    if (t >= 99720) return;
    const void* src; int i; int off;
    if      (t < 32768) { src = a0; i = t;         off = 0;     }   // W_proj 256x128
    else if (t < 32896) { src = a1; i = t - 32768; off = 32768; }   // b_proj 128
    else if (t < 33024) { src = a2; i = t - 32896; off = 32896; }   // gamma 128
    else if (t < 33152) { src = a3; i = t - 33024; off = 33024; }   // beta 128
    else if (t < 33280) { src = a4; i = t - 33152; off = 33152; }   // q_w 128
    else if (t < 33281) { src = a5; i = t - 33280; off = 33280; }   // q_b 1
    else if (t < 98817) { src = a6; i = t - 33281; off = 33296; }   // conv_w 4x128x128
    else if (t < 99713) { src = a7; i = t - 98817; off = 98832; }   // cls_w 128x7
    else                { src = a8; i = t - 99713; off = 99728; }   // cls_b 7
    float v;
    if (*flag) v = ((const float*)src)[i];
    else       v = bf2f1(((const uint16_t*)src)[i]);
    dst[off + i] = v;
}

// ---------------- split-bf16 transposed weight prep ----------------
__global__ __launch_bounds__(256) void k_wsplit(const float* __restrict__ stg,
                                                uint16_t* __restrict__ wpThi, uint16_t* __restrict__ wpTlo,
                                                uint16_t* __restrict__ cwThi, uint16_t* __restrict__ cwTlo) {
    int t = blockIdx.x * 256 + threadIdx.x;
    if (t >= 32768 + 65536) return;
    float v; size_t dst; uint16_t *ha, *la;
    if (t < 32768) {
        int k = t >> 7, c = t & 127;
        v = stg[t];
        dst = (size_t)c * 256 + k; ha = wpThi; la = wpTlo;
    } else {
        int u = t - 32768;
        int L = u >> 14, rem = u & 16383;
        int k = rem >> 7, c = rem & 127;
        v = stg[33296 + u];
        dst = (size_t)L * 16384 + (size_t)c * 128 + k; ha = cwThi; la = cwTlo;
    }
    uint16_t hb = f2bf(v);
    uint16_t lb = f2bf(v - bf2f1(hb));
    ha[dst] = hb; la[dst] = lb;
}

// ---------------- graph prep: atomic-free counting-sort CSR build ----------------

// pass 1: per-chunk LDS histogram over row-buckets (no global atomics)
__global__ __launch_bounds__(256) void k_hist(const int* __restrict__ row, int* __restrict__ hist) {
    __shared__ int lh[NBK];
    int b = blockIdx.x, tid = threadIdx.x;
    for (int i = tid; i < NBK; i += 256) lh[i] = 0;
    __syncthreads();
    int e0 = b * CHUNK;
    int lim = N_EDGES - e0; if (lim > CHUNK) lim = CHUNK;
    for (int i = tid; i < lim; i += 256) atomicAdd(&lh[row[e0 + i] >> BSHIFT], 1);
    __syncthreads();
    for (int i = tid; i < NBK; i += 256) hist[(size_t)b * NBK + i] = lh[i];
}

// pass 2a: per-bucket exclusive scan over chunks; emit bucket totals
__global__ __launch_bounds__(128) void k_hscan(int* __restrict__ hist, int* __restrict__ totB) {
    __shared__ int s[128];
    int bkt = blockIdx.x, t = threadIdx.x;
    int v = (t < NCH) ? hist[(size_t)t * NBK + bkt] : 0;
    s[t] = v;
    __syncthreads();
    for (int off = 1; off < 128; off <<= 1) {
        int add = (t >= off) ? s[t - off] : 0;
        __syncthreads();
        s[t] += add;
        __syncthreads();
    }
    if (t < NCH) hist[(size_t)t * NBK + bkt] = s[t] - v;   // exclusive within bucket
    if (t == 127) totB[bkt] = s[127];
}

// pass 2b: exclusive scan of bucket totals -> global bucket offsets
__global__ __launch_bounds__(256) void k_bscan(const int* __restrict__ totB,
                                               int* __restrict__ boffB, int* __restrict__ rp) {
    __shared__ int ps[256];
    int t = threadIdx.x;
    const int STRIP = 7;                     // 256*7 = 1792 >= NBK
    int base = t * STRIP;
    int loc[STRIP]; int sum = 0;
#pragma unroll
    for (int j = 0; j < STRIP; j++) {
        int idx = base + j;
        int v = (idx < NBK) ? totB[idx] : 0;
        loc[j] = sum; sum += v;
    }
    ps[t] = sum;
    __syncthreads();
    int v = ps[t];
    for (int off = 1; off < 256; off <<= 1) {
        int add = (t >= off) ? ps[t - off] : 0;
        __syncthreads();
        ps[t] += add;
        __syncthreads();
    }
    int excl = ps[t] - v;
#pragma unroll
    for (int j = 0; j < STRIP; j++) {
        int idx = base + j;
        if (idx < NBK) boffB[idx] = excl + loc[j];
    }
    if (t == 0) { boffB[NBK] = N_EDGES; rp[N_NODES] = N_EDGES; }
}

// pass 3: rank in LDS, scatter packed (row&63)<<17 | col  (4B, no global atomics)
__global__ __launch_bounds__(256) void k_sortscat(const int* __restrict__ row, const int* __restrict__ col,
                                                  const int* __restrict__ hist, const int* __restrict__ boffB,
                                                  uint32_t* __restrict__ ebp) {
    __shared__ int dbase[NBK];
    __shared__ int lcnt[NBK];
    int b = blockIdx.x, tid = threadIdx.x;
    for (int i = tid; i < NBK; i += 256) {
        dbase[i] = boffB[i] + hist[(size_t)b * NBK + i];
        lcnt[i] = 0;
    }
    __syncthreads();
    int e0 = b * CHUNK;
    int lim = N_EDGES - e0; if (lim > CHUNK) lim = CHUNK;
    for (int i = tid; i < lim; i += 256) {
        int r = row[e0 + i], c = col[e0 + i];
        int bk = r >> BSHIFT;
        int rank = atomicAdd(&lcnt[bk], 1);
        ebp[dbase[bk] + rank] = ((uint32_t)(r & (BROWS - 1)) << 17) | (uint32_t)c;
    }
}

// pass 4: per bucket -> degrees, rp, dis, final col-only CSR (4KB private write window)
__global__ __launch_bounds__(256) void k_bfin(const uint32_t* __restrict__ ebp, const int* __restrict__ boffB,
                                              int* __restrict__ rp, float* __restrict__ dis,
                                              int* __restrict__ edc) {
    __shared__ int ldeg[BROWS];
    __shared__ int lcur[BROWS];
    int b = blockIdx.x, tid = threadIdx.x;
    int base = boffB[b];
    int n = boffB[b + 1] - base;
    if (tid < BROWS) ldeg[tid] = 0;
    __syncthreads();
    for (int i = tid; i < n; i += 256) atomicAdd(&ldeg[ebp[base + i] >> 17], 1);
    __syncthreads();
    if (tid == 0) {
        int run = 0;
        for (int r = 0; r < BROWS; r++) { int d = ldeg[r]; lcur[r] = run; run += d; }
    }
    __syncthreads();
    int row0 = b << BSHIFT;
    if (tid < BROWS && row0 + tid < N_NODES) {
        int d = ldeg[tid];
        rp[row0 + tid]  = base + lcur[tid];
        dis[row0 + tid] = rsqrtf((float)(d > 0 ? d : 1));
    }
    __syncthreads();   // rp/dis read lcur before scatter mutates it
    for (int i = tid; i < n; i += 256) {
        uint32_t pk = ebp[base + i];
        int r = pk >> 17;
        int pos = atomicAdd(&lcur[r], 1);
        edc[base + pos] = (int)(pk & 0x1FFFFu);
    }
}

// ---------------- fused SpMM + blend ----------------
// one wave per node; lane holds cols {lane, lane+64}.
// edge = col only; weight = ScD[c] (= quantScale*dis folded), row factor dis[r] applied once.

__global__ __launch_bounds__(256) void k_spmm(const uint32_t* __restrict__ Hq,
                                              const float* __restrict__ ScD,
                                              const float* __restrict__ H0,
                                              const int* __restrict__ rp,
                                              const int* __restrict__ edc,
                                              const float* __restrict__ S,
                                              const float* __restrict__ dis,
                                              float* __restrict__ Sup) {
    int wid  = (blockIdx.x * 256 + threadIdx.x) >> 6;
    int lane = threadIdx.x & 63;
    if (wid >= N_NODES) return;

    float s  = S[wid];
    float dr = dis[wid];

    int p0 = rp[wid], p1 = rp[wid + 1];
    float ax = 0.f, ay = 0.f;
    int p = p0;
    for (; p + 4 <= p1; p += 4) {
        int c0 = edc[p], c1 = edc[p + 1], c2 = edc[p + 2], c3 = edc[p + 3];
        uint32_t u0 = Hq[(size_t)c0 * 64 + lane];
        uint32_t u1 = Hq[(size_t)c1 * 64 + lane];
        uint32_t u2 = Hq[(size_t)c2 * 64 + lane];
        uint32_t u3 = Hq[(size_t)c3 * 64 + lane];
        float w0 = ScD[c0], w1 = ScD[c1], w2 = ScD[c2], w3 = ScD[c3];
        ax += w0 * (float)((int)(u0 << 16) >> 16) + w1 * (float)((int)(u1 << 16) >> 16)
            + w2 * (float)((int)(u2 << 16) >> 16) + w3 * (float)((int)(u3 << 16) >> 16);
        ay += w0 * (float)((int)u0 >> 16) + w1 * (float)((int)u1 >> 16)
            + w2 * (float)((int)u2 >> 16) + w3 * (float)((int)u3 >> 16);
    }
    for (; p < p1; p++) {
        int c = edc[p];
        uint32_t u = Hq[(size_t)c * 64 + lane];
        float w = ScD[c];
        ax += w * (float)((int)(u << 16) >> 16);
        ay += w * (float)((int)u >> 16);
    }
    float h0x = H0[(size_t)wid * 128 + lane];
    float h0y = H0[(size_t)wid * 128 + 64 + lane];
    float f = (1.f - s) * dr;
    Sup[(size_t)wid * 128 + lane]      = f * ax + s * h0x;
    Sup[(size_t)wid * 128 + 64 + lane] = f * ay + s * h0y;
}

// ---------------- split-bf16 MFMA GEMM + fused LN + gate + quant ----------------
// Block = 64 rows x 128 cols, 256 threads = 4 waves; wave w owns rows [w*16, w*16+16).
// C layout: col = lane&15, row = (lane>>4)*4 + reg.  Split: C = Ah*Wh + Ah*Wl + Al*Wh.
// LDS tiles XOR-swizzled (byte ^= (row&7)<<4), applied identically on write and read.
// NOTE: Hout may alias Araw for MODE 1 (each row read/written only by its own 16 lanes).

template <int KD, int MODE, int WH, int WQ>
__global__ __launch_bounds__(256) void k_gemm_mfma(
    const void* __restrict__ Araw,       // [N][KD] fp32 (or bf16 if MODE0 && !flag)
    const uint16_t* __restrict__ WThi,   // [128][KD] bf16 hi (transposed)
    const uint16_t* __restrict__ WTlo,   // [128][KD] bf16 lo
    const float* __restrict__ bias, const float* __restrict__ gamma,
    const float* __restrict__ beta, const float* __restrict__ qw,
    const float* __restrict__ qb, float theta, const int* __restrict__ flag,
    const float* __restrict__ dis,
    float* __restrict__ Hout, uint32_t* __restrict__ Hq,
    float* __restrict__ Sc, float* __restrict__ S)
{
    __shared__ __align__(16) uint16_t sAhi[64 * 64];    // 8 KiB
    __shared__ __align__(16) uint16_t sAlo[64 * 64];    // 8 KiB
    __shared__ __align__(16) uint16_t sBhi[128 * 64];   // 16 KiB
    __shared__ __align__(16) uint16_t sBlo[128 * 64];   // 16 KiB  -> 48 KiB total

    const int tid  = threadIdx.x;
    const int lane = tid & 63;
    const int wv   = tid >> 6;
    const int li   = lane & 15;
    const int lg   = lane >> 4;
    const size_t row0 = (size_t)blockIdx.x * 64;
    const int f32in = (MODE == 0) ? *flag : 1;

    f32x4 acc[8];
#pragma unroll
    for (int ct = 0; ct < 8; ct++) acc[ct] = (f32x4){0.f, 0.f, 0.f, 0.f};

    for (int kc = 0; kc < KD / 64; kc++) {
        __syncthreads();
        // ---- stage A (64 rows x 64 k) as hi/lo bf16, swizzled ----
#pragma unroll
        for (int it = 0; it < 2; it++) {
            int s  = tid + it * 256;
            int r  = s >> 3, sl = s & 7;
            size_t rg = row0 + r; if (rg >= N_NODES) rg = N_NODES - 1;
            uint4 vh, vl;
            if (f32in) {
                const float* p = (const float*)Araw + rg * KD + kc * 64 + sl * 8;
                float4 u0 = *(const float4*)p;
                float4 u1 = *(const float4*)(p + 4);
                float f[8] = {u0.x, u0.y, u0.z, u0.w, u1.x, u1.y, u1.z, u1.w};
                uint32_t hw[8], lw[8];
#pragma unroll
                for (int j = 0; j < 8; j++) {
                    uint16_t hb = f2bf(f[j]);
                    uint16_t lb = f2bf(f[j] - bf2f1(hb));
                    hw[j] = hb; lw[j] = lb;
                }
                vh.x = hw[0] | (hw[1] << 16); vh.y = hw[2] | (hw[3] << 16);
                vh.z = hw[4] | (hw[5] << 16); vh.w = hw[6] | (hw[7] << 16);
                vl.x = lw[0] | (lw[1] << 16); vl.y = lw[2] | (lw[3] << 16);
                vl.z = lw[4] | (lw[5] << 16); vl.w = lw[6] | (lw[7] << 16);
            } else {
                vh = *(const uint4*)((const uint16_t*)Araw + rg * KD + kc * 64 + sl * 8);
                vl.x = 0u; vl.y = 0u; vl.z = 0u; vl.w = 0u;
            }
            uint32_t byte = (uint32_t)(r * 128 + sl * 16) ^ (uint32_t)((r & 7) << 4);
            *(uint4*)((char*)sAhi + byte) = vh;
            *(uint4*)((char*)sAlo + byte) = vl;
        }
        // ---- stage W^T (128 cols x 64 k), swizzled ----
#pragma unroll
        for (int it = 0; it < 4; it++) {
            int s = tid + it * 256;
            int r = s >> 3, sl = s & 7;
            size_t gsrc = (size_t)r * KD + kc * 64 + sl * 8;
            uint4 vh = *(const uint4*)(WThi + gsrc);
            uint4 vl = *(const uint4*)(WTlo + gsrc);
            uint32_t byte = (uint32_t)(r * 128 + sl * 16) ^ (uint32_t)((r & 7) << 4);
            *(uint4*)((char*)sBhi + byte) = vh;
            *(uint4*)((char*)sBlo + byte) = vl;
        }
        __syncthreads();
        // ---- MFMA: 2 K-steps of 32 per chunk ----
#pragma unroll
        for (int ks = 0; ks < 2; ks++) {
            int arow = wv * 16 + li;
            uint32_t ab = (uint32_t)(arow * 128 + ks * 64 + lg * 16) ^ (uint32_t)((arow & 7) << 4);
            bf16x8 ah = *(const bf16x8*)((const char*)sAhi + ab);
            bf16x8 al = *(const bf16x8*)((const char*)sAlo + ab);
#pragma unroll
            for (int ct = 0; ct < 8; ct++) {
                int brow = ct * 16 + li;
                uint32_t bb = (uint32_t)(brow * 128 + ks * 64 + lg * 16) ^ (uint32_t)((brow & 7) << 4);
                bf16x8 bh = *(const bf16x8*)((const char*)sBhi + bb);
                bf16x8 bl = *(const bf16x8*)((const char*)sBlo + bb);
                acc[ct] = __builtin_amdgcn_mfma_f32_16x16x32_bf16(ah, bh, acc[ct], 0, 0, 0);
                acc[ct] = __builtin_amdgcn_mfma_f32_16x16x32_bf16(ah, bl, acc[ct], 0, 0, 0);
                acc[ct] = __builtin_amdgcn_mfma_f32_16x16x32_bf16(al, bh, acc[ct], 0, 0, 0);
            }
        }
    }

    // ---- epilogue ----
    float gm[8], bt[8], qv[8], bi[8];
#pragma unroll
    for (int ct = 0; ct < 8; ct++) {
        int c = ct * 16 + li;
        gm[ct] = gamma[c]; bt[ct] = beta[c]; qv[ct] = qw[c];
        bi[ct] = (MODE == 0) ? bias[c] : 0.f;
    }
    const float qbv = qb[0];
    const float om  = 1.f - theta;
    const float* Af = (const float*)Araw;

#pragma unroll
    for (int r = 0; r < 4; r++) {
        int rowl  = wv * 16 + lg * 4 + r;
        size_t rg = row0 + rowl;
        size_t rc = (rg < N_NODES) ? rg : (N_NODES - 1);
        float v[8];
        if (MODE == 0) {
#pragma unroll
            for (int ct = 0; ct < 8; ct++) v[ct] = acc[ct][r] + bi[ct];
        } else {
#pragma unroll
            for (int ct = 0; ct < 8; ct++) {
                float sv = Af[rc * KD + ct * 16 + li];   // support re-read (L1/L2-hot)
                float o  = theta * acc[ct][r] + om * sv;
                v[ct] = o > 0.f ? o : 0.f;
            }
        }
        float sum = 0.f, sq = 0.f;
#pragma unroll
        for (int ct = 0; ct < 8; ct++) { sum += v[ct]; sq += v[ct] * v[ct]; }
        sum += __shfl_xor(sum, 1); sum += __shfl_xor(sum, 2);
        sum += __shfl_xor(sum, 4); sum += __shfl_xor(sum, 8);
        sq  += __shfl_xor(sq, 1);  sq  += __shfl_xor(sq, 2);
        sq  += __shfl_xor(sq, 4);  sq  += __shfl_xor(sq, 8);
        float mu  = sum * (1.f / 128.f);
        float var = fmaxf(sq * (1.f / 128.f) - mu * mu, 0.f);
        float rs  = rsqrtf(var + LN_EPS);
        float y[8];
#pragma unroll
        for (int ct = 0; ct < 8; ct++) y[ct] = gm[ct] * (v[ct] - mu) * rs + bt[ct];

        if (WQ) {
            float zd = 0.f, am = 0.f;
#pragma unroll
            for (int ct = 0; ct < 8; ct++) { zd += y[ct] * qv[ct]; am = fmaxf(am, fabsf(y[ct])); }
            zd += __shfl_xor(zd, 1); zd += __shfl_xor(zd, 2);
            zd += __shfl_xor(zd, 4); zd += __shfl_xor(zd, 8);
            am = fmaxf(am, __shfl_xor(am, 1)); am = fmaxf(am, __shfl_xor(am, 2));
            am = fmaxf(am, __shfl_xor(am, 4)); am = fmaxf(am, __shfl_xor(am, 8));
            float amc  = fmaxf(am, 1e-20f);
            float qinv = 32767.f / amc;
            if (rg < N_NODES) {
                uint32_t* mq = Hq + rg * 64;
#pragma unroll
                for (int ct = 0; ct < 4; ct++)
                    mq[ct * 16 + li] = packq(y[ct], y[ct + 4], qinv);  // pair (c, c+64)
                if (li == 0) {
                    Sc[rg] = amc * (1.f / 32767.f) * dis[rg];   // fold dis[col] into scale
                    S[rg]  = 1.f / (1.f + __expf(-(zd + qbv - 1.f)));
                }
            }
        }
        if (WH && rg < N_NODES) {
            float* dst = Hout + rg * 128;
#pragma unroll
            for (int ct = 0; ct < 8; ct++) dst[ct * 16 + li] = y[ct];
        }
    }
}

// ---------------- classifier (fp32 in, dtype-flag out) ----------------

__global__ __launch_bounds__(256) void k_cls(const float* __restrict__ H,
                                             const float* __restrict__ Wc,
                                             const float* __restrict__ bc,
                                             const int* __restrict__ flag,
                                             void* __restrict__ out) {
    __shared__ float wS[128][8];
    int tid = threadIdx.x;
    for (int idx = tid; idx < 128 * 7; idx += 256) wS[idx / 7][idx % 7] = Wc[idx];
    __syncthreads();
    int isf32 = *flag;
    int gid = blockIdx.x * 256 + tid;
    int n = gid >> 3, j = gid & 7;
    if (n >= N_NODES || j >= OUT_DIM) return;
    const float4* hr = (const float4*)(H + (size_t)n * 128);
    float acc = bc[j];
#pragma unroll
    for (int k4 = 0; k4 < 32; k4++) {
        float4 h4 = hr[k4];
        acc += h4.x * wS[4 * k4][j]     + h4.y * wS[4 * k4 + 1][j]
             + h4.z * wS[4 * k4 + 2][j] + h4.w * wS[4 * k4 + 3][j];
    }
    size_t oi = (size_t)n * OUT_DIM + j;
    if (isf32) ((float*)out)[oi] = acc;
    else       ((uint16_t*)out)[oi] = f2bf(acc);
}

// ---------------- launch ----------------

extern "C" void kernel_launch(void* const* d_in, const int* in_sizes, int n_in,
                              void* d_out, int out_size, void* d_ws, size_t ws_size,
                              hipStream_t stream) {
    const void* x_raw = d_in[0];
    const int*  ei    = (const int*)d_in[1];
    const int* row = ei;
    const int* col = ei + N_EDGES;

    char* ws = (char*)d_ws;
    size_t off = 0;
    auto alloc = [&](size_t b) { void* p = ws + off; off = (off + b + 255) & ~(size_t)255; return p; };
    int*      flag = (int*)alloc(4);
    float*    stgf = (float*)alloc((size_t)99744 * 4);
    int*      rp   = (int*)alloc(((size_t)N_NODES + 1) * 4);
    float*    dis  = (float*)alloc((size_t)N_NODES * 4);
    int*      hist = (int*)alloc((size_t)NCH * NBK * 4);          // 613 KB
    int*      totB = (int*)alloc((size_t)NBK * 4);
    int*      boffB= (int*)alloc(((size_t)NBK + 1) * 4);
    int*      edc  = (int*)alloc((size_t)N_EDGES * 4);            // CSR cols (4B)
    float*    h0   = (float*)alloc((size_t)N_NODES * HID * 4);
    float*    sup  = (float*)alloc((size_t)N_NODES * HID * 4);    // also final h (in-place)
    uint32_t* hq   = (uint32_t*)alloc((size_t)N_NODES * 64 * 4);  // int16 mirror
    float*    Scq  = (float*)alloc((size_t)N_NODES * 4);          // quant scale * dis
    float*    Sg   = (float*)alloc((size_t)N_NODES * 4);          // gate sigmoid
    uint16_t* wpThi = (uint16_t*)alloc((size_t)32768 * 2);
    uint16_t* wpTlo = (uint16_t*)alloc((size_t)32768 * 2);
    uint16_t* cwThi = (uint16_t*)alloc((size_t)65536 * 2);
    uint16_t* cwTlo = (uint16_t*)alloc((size_t)65536 * 2);
    uint32_t* ebp  = (uint32_t*)h0;   // bucket-sorted packed edges (6.4MB) alias h0

    const float* bp  = stgf + 32768;
    const float* gm  = stgf + 32896;
    const float* bt  = stgf + 33024;
    const float* qw  = stgf + 33152;
    const float* qb  = stgf + 33280;
    const float* clw = stgf + 98832;
    const float* clb = stgf + 99728;

    k_detect<<<1, 64, 0, stream>>>((const uint32_t*)d_in[2], flag);
    k_cvt<<<(99720 + 255) / 256, 256, 0, stream>>>(d_in[2], d_in[3], d_in[4], d_in[5], d_in[6],
                                                   d_in[7], d_in[8], d_in[9], d_in[10], stgf, flag);
    k_wsplit<<<(98304 + 255) / 256, 256, 0, stream>>>(stgf, wpThi, wpTlo, cwThi, cwTlo);

    k_hist<<<NCH, 256, 0, stream>>>(row, hist);
    k_hscan<<<NBK, 128, 0, stream>>>(hist, totB);
    k_bscan<<<1, 256, 0, stream>>>(totB, boffB, rp);
    k_sortscat<<<NCH, 256, 0, stream>>>(row, col, hist, boffB, ebp);
    k_bfin<<<NBK, 256, 0, stream>>>(ebp, boffB, rp, dis, edc);

    const int gemm_grid = (N_NODES + 63) / 64;   // 1563
    k_gemm_mfma<IN_DIM, 0, 1, 1><<<gemm_grid, 256, 0, stream>>>(
        x_raw, wpThi, wpTlo, bp, gm, bt, qw, qb, 0.f, flag, dis, h0, hq, Scq, Sg);

    for (int i = 0; i < N_LAYERS; i++) {
        k_spmm<<<(N_NODES + 3) / 4, 256, 0, stream>>>(hq, Scq, h0, rp, edc, Sg, dis, sup);
        float theta = 0.5f / (float)(i + 1);
        const uint16_t* whi = cwThi + (size_t)i * 16384;
        const uint16_t* wlo = cwTlo + (size_t)i * 16384;
        if (i < N_LAYERS - 1) {
            k_gemm_mfma<HID, 1, 0, 1><<<gemm_grid, 256, 0, stream>>>(
                sup, whi, wlo, nullptr, gm, bt, qw, qb, theta, flag, dis, sup, hq, Scq, Sg);
        } else {
            k_gemm_mfma<HID, 1, 1, 0><<<gemm_grid, 256, 0, stream>>>(
                sup, whi, wlo, nullptr, gm, bt, qw, qb, theta, flag, dis, sup, hq, Scq, Sg);
        }
    }
    k_cls<<<((size_t)N_NODES * 8 + 255) / 256, 256, 0, stream>>>(sup, clw, clb, flag, d_out);
}